// Round 7
// baseline (3812.654 us; speedup 1.0000x reference)
//
#include <hip/hip_runtime.h>

// ---------------------------------------------------------------------------
// ConditionedLatentSDETransition — MI355X (round 7: fp32 OUTPUTS)
//
// Root cause of rounds 3-6: harness decodes d_out as float32 (reference
// output dtype), we were writing bf16 ushorts. This round: identical fp32
// pipeline, outputs written as float32.
//
// Per step: X1=z@W1^T+b1 -> BN+relu (in-place) -> X2=A1@W2^T+b2 -> BN+relu
//           F=A2@W3^T+b3; T=tanh(z@Wd1^T+bd1); G=softplus(T@Wd2^T+bd2)+1e-5
//           z += h*F + sqrt_h*G*eps[s]
// Final: z_next = z + dt*(ut@B_sde^T); yt = z_next@C^T + dt*(ut@D^T)
// ---------------------------------------------------------------------------

typedef unsigned short ushort_t;

__device__ __forceinline__ float bf2f(ushort_t s) {
  unsigned u = ((unsigned)s) << 16;
  return __uint_as_float(u);
}
__device__ __forceinline__ float ldin(const void* p, size_t i, int f32) {
  return f32 ? ((const float*)p)[i] : bf2f(((const ushort_t*)p)[i]);
}

// consts: [0]=h, [1]=sqrt_h, [2]=dt, [3]=f32flag
__global__ void k_detect(const void* __restrict__ eps, const void* __restrict__ dtraw,
                         float* __restrict__ consts) {
  __shared__ float mx[256];
  const int t = threadIdx.x;
  const ushort_t* e = (const ushort_t*)eps;
  float m = 0.f;
#pragma unroll
  for (int k = 0; k < 4; ++k) {
    float v = fabsf(bf2f(e[t * 4 + k]));
    if (!(v < 1e30f)) v = 1e30f;
    m = fmaxf(m, v);
  }
  mx[t] = m;
  __syncthreads();
  if (t == 0) {
    float M = 0.f;
    for (int k = 0; k < 256; ++k) M = fmaxf(M, mx[k]);
    const int f32 = (M > 1e3f) ? 1 : 0;
    float dt;
    if (f32) {
      dt = *(const float*)dtraw;
    } else {
      float db = bf2f(*(const ushort_t*)dtraw);
      float df = *(const float*)dtraw;
      dt = (db > 1e-6f && db < 1e3f) ? db : df;
    }
    const float h = dt * 0.125f;
    consts[0] = h;
    consts[1] = sqrtf(fabsf(h) + 1e-8f);
    consts[2] = dt;
    consts[3] = (float)f32;
  }
}

// ---------------------------------------------------------------------------
// fp32 GEMM: C[m][n] = act( sum_k A[m][k]*W[n][k] + bias[n] )
// A: fp32 (M,K). W/bias: raw input (flag dtype). C: fp32 (M,N).
// 64x64 tile, BK=32, 256 threads, 4x4 acc. MODE 0 plain, 1 tanh, 2 softplus.
// ---------------------------------------------------------------------------
template <int MODE>
__global__ __launch_bounds__(256) void sgemm(
    const float* __restrict__ A, const void* __restrict__ W,
    const void* __restrict__ bias, float* __restrict__ Cout,
    const float* __restrict__ consts, int M, int N, int K) {
  __shared__ float As[32][68];  // [k][m]
  __shared__ float Bs[32][68];  // [k][n]
  const int f32 = consts[3] != 0.f;
  const int t = threadIdx.x;
  const int tx = t & 15, ty = t >> 4;
  const int m0 = blockIdx.y * 64, n0 = blockIdx.x * 64;
  const int r = t >> 2;        // staging row 0..63
  const int c0 = (t & 3) * 8;  // staging k-offset {0,8,16,24}

  float acc[4][4] = {};

  for (int k0 = 0; k0 < K; k0 += 32) {
    {  // A tile -> As[k][m]
      const float* src = A + (size_t)(m0 + r) * K + k0 + c0;
      float4 a0 = *(const float4*)src;
      float4 a1 = *(const float4*)(src + 4);
      float v[8] = {a0.x, a0.y, a0.z, a0.w, a1.x, a1.y, a1.z, a1.w};
#pragma unroll
      for (int j = 0; j < 8; ++j) As[c0 + j][r] = v[j];
    }
    {  // W tile -> Bs[k][n]
      float v[8];
      if (f32) {
        const float* src = (const float*)W + (size_t)(n0 + r) * K + k0 + c0;
        float4 a0 = *(const float4*)src;
        float4 a1 = *(const float4*)(src + 4);
        v[0] = a0.x; v[1] = a0.y; v[2] = a0.z; v[3] = a0.w;
        v[4] = a1.x; v[5] = a1.y; v[6] = a1.z; v[7] = a1.w;
      } else {
        const ushort_t* src = (const ushort_t*)W + (size_t)(n0 + r) * K + k0 + c0;
        ushort4 u0 = *(const ushort4*)src;
        ushort4 u1 = *(const ushort4*)(src + 4);
        v[0] = bf2f(u0.x); v[1] = bf2f(u0.y); v[2] = bf2f(u0.z); v[3] = bf2f(u0.w);
        v[4] = bf2f(u1.x); v[5] = bf2f(u1.y); v[6] = bf2f(u1.z); v[7] = bf2f(u1.w);
      }
#pragma unroll
      for (int j = 0; j < 8; ++j) Bs[c0 + j][r] = v[j];
    }
    __syncthreads();

#pragma unroll
    for (int kk = 0; kk < 32; ++kk) {
      float a[4], b[4];
      *(float4*)a = *(const float4*)&As[kk][ty * 4];
      *(float4*)b = *(const float4*)&Bs[kk][tx * 4];
#pragma unroll
      for (int i = 0; i < 4; ++i)
#pragma unroll
        for (int j = 0; j < 4; ++j) acc[i][j] += a[i] * b[j];
    }
    __syncthreads();
  }

#pragma unroll
  for (int j = 0; j < 4; ++j) {
    const int n = n0 + tx * 4 + j;
    const float bv = ldin(bias, n, f32);
#pragma unroll
    for (int i = 0; i < 4; ++i) {
      const int m = m0 + ty * 4 + i;
      float v = acc[i][j] + bv;
      if (MODE == 1) {
        v = tanhf(v);
      } else if (MODE == 2) {
        v = fmaxf(v, 0.f) + log1pf(expf(-fabsf(v))) + 1e-5f;
      }
      Cout[(size_t)m * N + n] = v;
    }
  }
}

// per-column sum / sum^2 over 4096 rows (fp32, atomics)
__global__ void bn_stats(const float* __restrict__ X, float* __restrict__ s1,
                         float* __restrict__ s2, int N) {
  __shared__ float ls[2][4][64];
  const int t = threadIdx.x;
  const int cl = t & 63;
  const int rg = t >> 6;
  const int c = blockIdx.x * 64 + cl;
  const int r0 = blockIdx.y * 256 + rg * 64;
  float s = 0.f, q = 0.f;
  for (int i = 0; i < 64; ++i) {
    float v = X[(size_t)(r0 + i) * N + c];
    s += v;
    q += v * v;
  }
  ls[0][rg][cl] = s;
  ls[1][rg][cl] = q;
  __syncthreads();
  if (t < 64) {
    float S = ls[0][0][t] + ls[0][1][t] + ls[0][2][t] + ls[0][3][t];
    float Q = ls[1][0][t] + ls[1][1][t] + ls[1][2][t] + ls[1][3][t];
    atomicAdd(&s1[blockIdx.x * 64 + t], S);
    atomicAdd(&s2[blockIdx.x * 64 + t], Q);
  }
}

// BN normalize + relu, in-place, fp32
__global__ void bn_norm(float* __restrict__ X, const float* __restrict__ s1,
                        const float* __restrict__ s2, const void* __restrict__ g,
                        const void* __restrict__ be, const float* __restrict__ consts,
                        int N) {
  const int f32 = consts[3] != 0.f;
  const int i = blockIdx.x * 256 + threadIdx.x;
  const int c = (i * 4) % N;
  const float inv = 1.0f / 4096.0f;
  float4 x = ((const float4*)X)[i];
  float xv[4] = {x.x, x.y, x.z, x.w};
#pragma unroll
  for (int j = 0; j < 4; ++j) {
    float mu = s1[c + j] * inv;
    float var = fmaxf(s2[c + j] * inv - mu * mu, 0.f);
    float sc = ldin(g, c + j, f32) * rsqrtf(var + 1e-5f);
    float v = (xv[j] - mu) * sc + ldin(be, c + j, f32);
    xv[j] = fmaxf(v, 0.f);
  }
  ((float4*)X)[i] = make_float4(xv[0], xv[1], xv[2], xv[3]);
}

// zf <- z_dyn (flag dtype)
__global__ void k_init(const void* __restrict__ z, float* __restrict__ zf,
                       const float* __restrict__ consts) {
  const int f32 = consts[3] != 0.f;
  const int i = blockIdx.x * 256 + threadIdx.x;
  float4 v;
  if (f32) {
    v = ((const float4*)z)[i];
  } else {
    ushort4 u = ((const ushort4*)z)[i];
    v = make_float4(bf2f(u.x), bf2f(u.y), bf2f(u.z), bf2f(u.w));
  }
  ((float4*)zf)[i] = v;
}

// z += h*F + sqrt_h*G*eps[s]
__global__ void k_update(float* __restrict__ zf, const float* __restrict__ F,
                         const float* __restrict__ G, const void* __restrict__ E,
                         unsigned long long eoff, const float* __restrict__ consts) {
  const float h = consts[0], sh = consts[1];
  const int f32 = consts[3] != 0.f;
  const int i = blockIdx.x * 256 + threadIdx.x;
  float4 e;
  if (f32) {
    e = ((const float4*)((const float*)E + eoff))[i];
  } else {
    ushort4 u = ((const ushort4*)((const ushort_t*)E + eoff))[i];
    e = make_float4(bf2f(u.x), bf2f(u.y), bf2f(u.z), bf2f(u.w));
  }
  float4 z = ((float4*)zf)[i];
  float4 f = ((const float4*)F)[i];
  float4 g = ((const float4*)G)[i];
  z.x += h * f.x + sh * g.x * e.x;
  z.y += h * f.y + sh * g.y * e.y;
  z.z += h * f.z + sh * g.z * e.z;
  z.w += h * f.w + sh * g.w * e.w;
  ((float4*)zf)[i] = z;
}

// z_next = z + dt*(ut@B_sde^T) -> FP32 out0 and fp32 znf scratch
__global__ void k_final1(const float* __restrict__ zf, const void* __restrict__ ut,
                         const float* __restrict__ consts, const void* __restrict__ Bsde,
                         float* __restrict__ out0, float* __restrict__ znf) {
  const float dt = consts[2];
  const int f32 = consts[3] != 0.f;
  const int idx = blockIdx.x * 256 + threadIdx.x;
  const int m = idx >> 9, n = idx & 511;
  float acc = 0.f;
#pragma unroll 8
  for (int k = 0; k < 64; ++k)
    acc += ldin(ut, (size_t)m * 64 + k, f32) * ldin(Bsde, (size_t)n * 64 + k, f32);
  float v = zf[idx] + dt * acc;
  znf[idx] = v;
  out0[idx] = v;
}

// yt = z_next@C^T + dt*(ut@D^T) -> FP32 out1
__global__ void k_final2(const float* __restrict__ znf, const void* __restrict__ ut,
                         const float* __restrict__ consts, const void* __restrict__ Cm,
                         const void* __restrict__ Dm, float* __restrict__ out1) {
  const float dt = consts[2];
  const int f32 = consts[3] != 0.f;
  const int idx = blockIdx.x * 256 + threadIdx.x;
  if (idx >= 4096 * 25) return;
  const int m = idx / 25, j = idx % 25;
  float acc = 0.f;
  for (int k = 0; k < 512; ++k)
    acc += znf[(size_t)m * 512 + k] * ldin(Cm, (size_t)j * 512 + k, f32);
  float acc2 = 0.f;
#pragma unroll 8
  for (int k = 0; k < 64; ++k)
    acc2 += ldin(ut, (size_t)m * 64 + k, f32) * ldin(Dm, (size_t)j * 64 + k, f32);
  out1[idx] = acc + dt * acc2;
}

// diagnostic: overwrite out0[0] with 8192 + 512*code (fp32)
__global__ void k_probe(float* __restrict__ out0, int code) {
  if (threadIdx.x == 0 && blockIdx.x == 0)
    out0[0] = 8192.0f + 512.0f * (float)code;
}

// ---------------------------------------------------------------------------
extern "C" void kernel_launch(void* const* d_in, const int* in_sizes, int n_in,
                              void* d_out, int out_size, void* d_ws, size_t ws_size,
                              hipStream_t stream) {
  // Expected element counts, full dict order:
  static const int expA[22] = {
      2097152, 524288, 1,      262144, 16777216, 524288, 1024, 1024,
      1024,    1048576, 1024,  1024,   1024,     524288, 512,  262144,
      512,     262144, 512,    32768,  12800,    1600};

  // map[i] = d_in index of logical input i (dict order without z_static):
  // 0:z_dyn 1:dt 2:ut 3:eps 4:W1 5:b1 6:g1 7:be1 8:W2 9:b2 10:g2 11:be2
  // 12:W3 13:b3 14:Wd1 15:bd1 16:Wd2 17:bd2 18:B_sde 19:C 20:D
  int map[21];
  bool okA = (n_in == 22), okB = (n_in == 21);
  if (okA)
    for (int i = 0; i < 22; ++i)
      if (in_sizes[i] != expA[i]) { okA = false; break; }
  if (okB) {
    int j = 0;
    for (int i = 0; i < 22; ++i) {
      if (i == 1) continue;
      if (in_sizes[j] != expA[i]) { okB = false; break; }
      ++j;
    }
  }
  if (okA) {
    map[0] = 0;
    for (int i = 1; i < 21; ++i) map[i] = i + 1;
  } else if (okB) {
    for (int i = 0; i < 21; ++i) map[i] = i;
  } else {
    map[0] = 0;
    for (int i = 1; i < 21; ++i) map[i] = (i + 1 < n_in) ? i + 1 : n_in - 1;
  }

  const size_t MB = 1024 * 1024;
  const bool ws_ok = ws_size >= 40 * MB + 16384;
  int code = 0;
  if (!okA && !okB) code |= 1;
  if (!ws_ok) code |= 2;
  const bool probe = (code != 0);

  const void* z_dyn = d_in[map[0]];
  const void* dtp = d_in[map[1]];
  const void* ut = d_in[map[2]];
  const void* eps = d_in[map[3]];
  const void* W1 = d_in[map[4]];
  const void* b1 = d_in[map[5]];
  const void* g1 = d_in[map[6]];
  const void* be1 = d_in[map[7]];
  const void* W2 = d_in[map[8]];
  const void* b2 = d_in[map[9]];
  const void* g2 = d_in[map[10]];
  const void* be2 = d_in[map[11]];
  const void* W3 = d_in[map[12]];
  const void* b3 = d_in[map[13]];
  const void* Wd1 = d_in[map[14]];
  const void* bd1 = d_in[map[15]];
  const void* Wd2 = d_in[map[16]];
  const void* bd2 = d_in[map[17]];
  const void* Bsde = d_in[map[18]];
  const void* Cm = d_in[map[19]];
  const void* Dm = d_in[map[20]];

  // ws (40 MB + 12 KB):
  //  [0,8M)   zf fp32 4096x512
  //  [8,24M)  X fp32 4096x1024 (X1/A1) | F [8,16M) + T [16,24M) | znf [8,16M)
  //  [24,40M) Y fp32 4096x1024 (X2/A2) | G [24,32M)
  //  [40M..)  s1(4K), s2(4K), consts
  char* ws = (char*)d_ws;
  float* zf = (float*)(ws + 0);
  float* X = (float*)(ws + 8 * MB);
  float* F = (float*)(ws + 8 * MB);
  float* T = (float*)(ws + 16 * MB);
  float* Y = (float*)(ws + 24 * MB);
  float* G = (float*)(ws + 24 * MB);
  float* znf = (float*)(ws + 8 * MB);
  float* s1 = (float*)(ws + 40 * MB);
  float* s2 = s1 + 1024;
  float* consts = s1 + 2048;

  float* out_z = (float*)d_out;              // fp32 output 0: z_next (4096x512)
  float* out_y = out_z + 4096 * 512;         // fp32 output 1: yt (4096x25)

  const dim3 blk(256);

  k_detect<<<1, blk, 0, stream>>>(eps, dtp, consts);
  k_init<<<2048, blk, 0, stream>>>(z_dyn, zf, consts);

  for (int s = 0; s < 8; ++s) {
    // X1 = z @ W1^T + b1 (4096x1024, K=512)
    sgemm<0><<<dim3(16, 64), blk, 0, stream>>>(zf, W1, b1, X, consts, 4096, 1024, 512);
    hipMemsetAsync(s1, 0, 2048 * sizeof(float), stream);
    bn_stats<<<dim3(16, 16), blk, 0, stream>>>(X, s1, s2, 1024);
    bn_norm<<<4096, blk, 0, stream>>>(X, s1, s2, g1, be1, consts, 1024);  // A1

    // X2 = A1 @ W2^T + b2 (4096x1024, K=1024)
    sgemm<0><<<dim3(16, 64), blk, 0, stream>>>(X, W2, b2, Y, consts, 4096, 1024, 1024);
    hipMemsetAsync(s1, 0, 2048 * sizeof(float), stream);
    bn_stats<<<dim3(16, 16), blk, 0, stream>>>(Y, s1, s2, 1024);
    bn_norm<<<4096, blk, 0, stream>>>(Y, s1, s2, g2, be2, consts, 1024);  // A2

    // F = A2 @ W3^T + b3 (4096x512, K=1024)
    sgemm<0><<<dim3(8, 64), blk, 0, stream>>>(Y, W3, b3, F, consts, 4096, 512, 1024);
    // T = tanh(z @ Wd1^T + bd1)
    sgemm<1><<<dim3(8, 64), blk, 0, stream>>>(zf, Wd1, bd1, T, consts, 4096, 512, 512);
    // G = softplus(T @ Wd2^T + bd2) + 1e-5
    sgemm<2><<<dim3(8, 64), blk, 0, stream>>>(T, Wd2, bd2, G, consts, 4096, 512, 512);

    k_update<<<2048, blk, 0, stream>>>(zf, F, G, eps,
                                       (unsigned long long)s * 4096 * 512, consts);
  }

  k_final1<<<8192, blk, 0, stream>>>(zf, ut, consts, Bsde, out_z, znf);
  k_final2<<<400, blk, 0, stream>>>(znf, ut, consts, Cm, Dm, out_y);

  if (probe) k_probe<<<1, 64, 0, stream>>>(out_z, code);
}

// Round 8
// 1517.927 us; speedup vs baseline: 2.5118x; 2.5118x over previous
//
#include <hip/hip_runtime.h>

// ---------------------------------------------------------------------------
// ConditionedLatentSDETransition — MI355X (round 8: bf16 MFMA GEMMs)
//
// Verified facts: inputs fp32 (runtime-detected), outputs fp32, ws >= 40MB,
// input map = dict order (n_in==22, z_static unused). fp32 baseline passed
// with absmax 0.0156 (threshold 0.1006).
//
// This round: m97-style bf16 MFMA GEMMs (128x128 tile, BK=64,
// global_load_lds width-16), fp32 z master + bf16 shadow, bf16 activations,
// tiled k_final1, LDS-staged k_final2, partial-sum BN stats (no memsets).
// ---------------------------------------------------------------------------

typedef unsigned short ushort_t;
typedef __bf16 bf16x8 __attribute__((ext_vector_type(8)));
typedef float f32x4 __attribute__((ext_vector_type(4)));

__device__ __forceinline__ float bf2f(ushort_t s) {
  unsigned u = ((unsigned)s) << 16;
  return __uint_as_float(u);
}
__device__ __forceinline__ ushort_t f2bf(float f) {
  unsigned u = __float_as_uint(f);
  unsigned lsb = (u >> 16) & 1u;
  u += 0x7fffu + lsb;
  return (ushort_t)(u >> 16);
}
__device__ __forceinline__ float ldin(const void* p, size_t i, int f32) {
  return f32 ? ((const float*)p)[i] : bf2f(((const ushort_t*)p)[i]);
}
__device__ __forceinline__ void async16(const void* g, void* l) {
  __builtin_amdgcn_global_load_lds(
      (const __attribute__((address_space(1))) void*)g,
      (__attribute__((address_space(3))) void*)l, 16, 0, 0);
}

// consts: [0]=h, [1]=sqrt_h, [2]=dt, [3]=f32flag
__global__ void k_detect(const void* __restrict__ eps, const void* __restrict__ dtraw,
                         float* __restrict__ consts) {
  __shared__ float mx[256];
  const int t = threadIdx.x;
  const ushort_t* e = (const ushort_t*)eps;
  float m = 0.f;
#pragma unroll
  for (int k = 0; k < 4; ++k) {
    float v = fabsf(bf2f(e[t * 4 + k]));
    if (!(v < 1e30f)) v = 1e30f;
    m = fmaxf(m, v);
  }
  mx[t] = m;
  __syncthreads();
  if (t == 0) {
    float M = 0.f;
    for (int k = 0; k < 256; ++k) M = fmaxf(M, mx[k]);
    const int f32 = (M > 1e3f) ? 1 : 0;
    float dt;
    if (f32) {
      dt = *(const float*)dtraw;
    } else {
      float db = bf2f(*(const ushort_t*)dtraw);
      float df = *(const float*)dtraw;
      dt = (db > 1e-6f && db < 1e3f) ? db : df;
    }
    const float h = dt * 0.125f;
    consts[0] = h;
    consts[1] = sqrtf(fabsf(h) + 1e-8f);
    consts[2] = dt;
    consts[3] = (float)f32;
  }
}

// ---- one-time: convert 5 weight matrices to bf16 in ws ----
struct ConvArgs { const void* src[5]; };
#define CONV_TOT 2621440

__global__ void k_conv(ConvArgs a, const float* __restrict__ consts,
                       ushort_t* __restrict__ base) {
  constexpr int CUM[6] = {0, 524288, 1572864, 2097152, 2359296, 2621440};
  const int f32 = consts[3] != 0.f;
  const int i = (blockIdx.x * 256 + threadIdx.x) * 4;
  if (i >= CONV_TOT) return;
  int j = 0;
#pragma unroll
  for (int k = 1; k < 5; ++k)
    if (i >= CUM[k]) j = k;
  const int local = i - CUM[j];
  const void* s = a.src[j];
  ushort4 o;
  if (f32) {
    float4 v = ((const float4*)s)[local >> 2];
    o = make_ushort4(f2bf(v.x), f2bf(v.y), f2bf(v.z), f2bf(v.w));
  } else {
    o = ((const ushort4*)s)[local >> 2];
  }
  *(ushort4*)(base + i) = o;
}

// ---------------------------------------------------------------------------
// MFMA GEMM: C[m][n] = act( sum_k A[m][k]*W[n][k] + bias[n] )
// A,W bf16 row-major; bias raw-dtype; C bf16 out. 128x128 tile, BK=64.
// MODE 0 plain, 1 tanh, 2 softplus+1e-5.
// ---------------------------------------------------------------------------
template <int MODE>
__global__ __launch_bounds__(256, 2) void mgemm(
    const ushort_t* __restrict__ A, const ushort_t* __restrict__ W,
    const void* __restrict__ bias, ushort_t* __restrict__ Cout,
    const float* __restrict__ consts, int M, int N, int K) {
  __shared__ __bf16 As[128 * 64] __attribute__((aligned(16)));
  __shared__ __bf16 Bs[128 * 64] __attribute__((aligned(16)));

  const int f32 = consts[3] != 0.f;
  const int tid = threadIdx.x;
  const int lane = tid & 63;
  const int wave = tid >> 6;
  const int wm = wave >> 1, wn = wave & 1;
  const int m0 = blockIdx.y * 128, n0 = blockIdx.x * 128;
  const int col = lane & 15;
  const int quad = lane >> 4;

  f32x4 acc[4][4] = {};

  for (int k0 = 0; k0 < K; k0 += 64) {
#pragma unroll
    for (int j = 0; j < 4; ++j) {
      int chunk = j * 256 + tid;  // 0..1023, 8 bf16 per chunk
      int row = chunk >> 3;
      int kc = chunk & 7;
      const ushort_t* ga = A + (size_t)(m0 + row) * K + k0 + kc * 8;
      const ushort_t* gb = W + (size_t)(n0 + row) * K + k0 + kc * 8;
      async16(ga, (char*)As + chunk * 16);
      async16(gb, (char*)Bs + chunk * 16);
    }
    __syncthreads();

#pragma unroll
    for (int kk = 0; kk < 2; ++kk) {
      const int kb = kk * 32 + quad * 8;
      bf16x8 af[4], bfr[4];
#pragma unroll
      for (int mt = 0; mt < 4; ++mt)
        af[mt] = *(const bf16x8*)&As[(wm * 64 + mt * 16 + col) * 64 + kb];
#pragma unroll
      for (int nt = 0; nt < 4; ++nt)
        bfr[nt] = *(const bf16x8*)&Bs[(wn * 64 + nt * 16 + col) * 64 + kb];
#pragma unroll
      for (int mt = 0; mt < 4; ++mt)
#pragma unroll
        for (int nt = 0; nt < 4; ++nt)
          acc[mt][nt] = __builtin_amdgcn_mfma_f32_16x16x32_bf16(
              af[mt], bfr[nt], acc[mt][nt], 0, 0, 0);
    }
    __syncthreads();
  }

#pragma unroll
  for (int nt = 0; nt < 4; ++nt) {
    const int gn = n0 + wn * 64 + nt * 16 + col;
    const float bv = ldin(bias, gn, f32);
#pragma unroll
    for (int mt = 0; mt < 4; ++mt) {
#pragma unroll
      for (int r = 0; r < 4; ++r) {
        const int gm = m0 + wm * 64 + mt * 16 + quad * 4 + r;
        float v = acc[mt][nt][r] + bv;
        if (MODE == 1) {
          v = tanhf(v);
        } else if (MODE == 2) {
          v = fmaxf(v, 0.f) + log1pf(expf(-fabsf(v))) + 1e-5f;
        }
        Cout[(size_t)gm * N + gn] = f2bf(v);
      }
    }
  }
}

// per-column partial sums over 256-row slabs; s1p/s2p[16][1024], no atomics
__global__ void bn_stats(const ushort_t* __restrict__ X, float* __restrict__ s1p,
                         float* __restrict__ s2p, int N) {
  __shared__ float ls[2][4][64];
  const int t = threadIdx.x;
  const int cl = t & 63;
  const int rg = t >> 6;
  const int c = blockIdx.x * 64 + cl;
  const int r0 = blockIdx.y * 256 + rg * 64;
  float s = 0.f, q = 0.f;
  for (int i = 0; i < 64; ++i) {
    float v = bf2f(X[(size_t)(r0 + i) * N + c]);
    s += v;
    q += v * v;
  }
  ls[0][rg][cl] = s;
  ls[1][rg][cl] = q;
  __syncthreads();
  if (t < 64) {
    float S = ls[0][0][t] + ls[0][1][t] + ls[0][2][t] + ls[0][3][t];
    float Q = ls[1][0][t] + ls[1][1][t] + ls[1][2][t] + ls[1][3][t];
    s1p[blockIdx.y * 1024 + blockIdx.x * 64 + t] = S;
    s2p[blockIdx.y * 1024 + blockIdx.x * 64 + t] = Q;
  }
}

// reduce 16 partials -> s1,s2 (grid 8 x 256 covers 2*1024)
__global__ void k_redstats(const float* __restrict__ s1p, const float* __restrict__ s2p,
                           float* __restrict__ s1, float* __restrict__ s2) {
  const int i = blockIdx.x * 256 + threadIdx.x;  // 0..2047
  const int c = i & 1023;
  const float* src = (i < 1024) ? s1p : s2p;
  float* dst = (i < 1024) ? s1 : s2;
  float acc = 0.f;
#pragma unroll
  for (int y = 0; y < 16; ++y) acc += src[y * 1024 + c];
  dst[c] = acc;
}

// BN normalize + relu, in-place on bf16 X
__global__ void bn_norm(ushort_t* __restrict__ X, const float* __restrict__ s1,
                        const float* __restrict__ s2, const void* __restrict__ g,
                        const void* __restrict__ be, const float* __restrict__ consts,
                        int N) {
  const int f32 = consts[3] != 0.f;
  const int i = blockIdx.x * 256 + threadIdx.x;
  const int c = (i * 4) % N;
  const float inv = 1.0f / 4096.0f;
  ushort4 x = ((const ushort4*)X)[i];
  float xv[4] = {bf2f(x.x), bf2f(x.y), bf2f(x.z), bf2f(x.w)};
  ushort_t o[4];
#pragma unroll
  for (int j = 0; j < 4; ++j) {
    float mu = s1[c + j] * inv;
    float var = fmaxf(s2[c + j] * inv - mu * mu, 0.f);
    float sc = ldin(g, c + j, f32) * rsqrtf(var + 1e-5f);
    float v = (xv[j] - mu) * sc + ldin(be, c + j, f32);
    o[j] = f2bf(fmaxf(v, 0.f));
  }
  ((ushort4*)X)[i] = make_ushort4(o[0], o[1], o[2], o[3]);
}

// zf (fp32 master) + zb (bf16 shadow) <- z_dyn
__global__ void k_init(const void* __restrict__ z, float* __restrict__ zf,
                       ushort_t* __restrict__ zb, const float* __restrict__ consts) {
  const int f32 = consts[3] != 0.f;
  const int i = blockIdx.x * 256 + threadIdx.x;
  float4 v;
  if (f32) {
    v = ((const float4*)z)[i];
  } else {
    ushort4 u = ((const ushort4*)z)[i];
    v = make_float4(bf2f(u.x), bf2f(u.y), bf2f(u.z), bf2f(u.w));
  }
  ((float4*)zf)[i] = v;
  ((ushort4*)zb)[i] = make_ushort4(f2bf(v.x), f2bf(v.y), f2bf(v.z), f2bf(v.w));
}

// z += h*F + sqrt_h*G*eps[s]  (F,G bf16; eps raw)
__global__ void k_update(float* __restrict__ zf, ushort_t* __restrict__ zb,
                         const ushort_t* __restrict__ F, const ushort_t* __restrict__ G,
                         const void* __restrict__ E, unsigned long long eoff,
                         const float* __restrict__ consts) {
  const float h = consts[0], sh = consts[1];
  const int f32 = consts[3] != 0.f;
  const int i = blockIdx.x * 256 + threadIdx.x;
  float4 e;
  if (f32) {
    e = ((const float4*)((const float*)E + eoff))[i];
  } else {
    ushort4 u = ((const ushort4*)((const ushort_t*)E + eoff))[i];
    e = make_float4(bf2f(u.x), bf2f(u.y), bf2f(u.z), bf2f(u.w));
  }
  float4 z = ((float4*)zf)[i];
  ushort4 f = ((const ushort4*)F)[i];
  ushort4 g = ((const ushort4*)G)[i];
  z.x += h * bf2f(f.x) + sh * bf2f(g.x) * e.x;
  z.y += h * bf2f(f.y) + sh * bf2f(g.y) * e.y;
  z.z += h * bf2f(f.z) + sh * bf2f(g.z) * e.z;
  z.w += h * bf2f(f.w) + sh * bf2f(g.w) * e.w;
  ((float4*)zf)[i] = z;
  ((ushort4*)zb)[i] = make_ushort4(f2bf(z.x), f2bf(z.y), f2bf(z.z), f2bf(z.w));
}

// z_next = zf + dt*(ut@Bsde^T): LDS-tiled (64x64 tile, K=64)
__global__ __launch_bounds__(256) void k_final1(
    const float* __restrict__ zf, const void* __restrict__ ut,
    const float* __restrict__ consts, const void* __restrict__ Bsde,
    float* __restrict__ out0, float* __restrict__ znf) {
  __shared__ float As[64][68];  // [k][m]
  __shared__ float Bs[64][68];  // [k][n]
  const float dt = consts[2];
  const int f32 = consts[3] != 0.f;
  const int t = threadIdx.x;
  const int tx = t & 15, ty = t >> 4;
  const int n0 = blockIdx.x * 64, m0 = blockIdx.y * 64;
  const int r = t >> 2;         // 0..63
  const int c0 = (t & 3) * 16;  // 0,16,32,48

#pragma unroll
  for (int j = 0; j < 16; ++j) {
    As[c0 + j][r] = ldin(ut, (size_t)(m0 + r) * 64 + c0 + j, f32);
    Bs[c0 + j][r] = ldin(Bsde, (size_t)(n0 + r) * 64 + c0 + j, f32);
  }
  __syncthreads();

  float acc[4][4] = {};
#pragma unroll 8
  for (int kk = 0; kk < 64; ++kk) {
    float a[4], b[4];
    *(float4*)a = *(const float4*)&As[kk][ty * 4];
    *(float4*)b = *(const float4*)&Bs[kk][tx * 4];
#pragma unroll
    for (int i = 0; i < 4; ++i)
#pragma unroll
      for (int j = 0; j < 4; ++j) acc[i][j] += a[i] * b[j];
  }

#pragma unroll
  for (int i = 0; i < 4; ++i) {
    const int m = m0 + ty * 4 + i;
    const size_t o = (size_t)m * 512 + n0 + tx * 4;
    float4 z = *(const float4*)&zf[o];
    float4 v = make_float4(z.x + dt * acc[i][0], z.y + dt * acc[i][1],
                           z.z + dt * acc[i][2], z.w + dt * acc[i][3]);
    *(float4*)&out0[o] = v;
    *(float4*)&znf[o] = v;
  }
}

// yt = znf@C^T + dt*(ut@D^T): C,D staged in LDS, wave-per-row
__global__ __launch_bounds__(256) void k_final2(
    const float* __restrict__ znf, const void* __restrict__ ut,
    const float* __restrict__ consts, const void* __restrict__ Cm,
    const void* __restrict__ Dm, float* __restrict__ out1) {
  __shared__ float Cs[25 * 512];
  __shared__ float Ds[25 * 64];
  const float dt = consts[2];
  const int f32 = consts[3] != 0.f;
  const int t = threadIdx.x;
  for (int i = t; i < 25 * 512; i += 256) Cs[i] = ldin(Cm, i, f32);
  for (int i = t; i < 25 * 64; i += 256) Ds[i] = ldin(Dm, i, f32);
  __syncthreads();

  const int lane = t & 63;
  const int m = blockIdx.x * 4 + (t >> 6);
  float z8[8];
#pragma unroll
  for (int i = 0; i < 8; ++i) z8[i] = znf[(size_t)m * 512 + i * 64 + lane];
  const float u = ldin(ut, (size_t)m * 64 + lane, f32);

  for (int j = 0; j < 25; ++j) {
    float p = dt * u * Ds[j * 64 + lane];
#pragma unroll
    for (int i = 0; i < 8; ++i) p += z8[i] * Cs[j * 512 + i * 64 + lane];
#pragma unroll
    for (int off = 32; off > 0; off >>= 1) p += __shfl_down(p, off, 64);
    if (lane == 0) out1[m * 25 + j] = p;
  }
}

// ---------------------------------------------------------------------------
extern "C" void kernel_launch(void* const* d_in, const int* in_sizes, int n_in,
                              void* d_out, int out_size, void* d_ws, size_t ws_size,
                              hipStream_t stream) {
  static const int expA[22] = {
      2097152, 524288, 1,      262144, 16777216, 524288, 1024, 1024,
      1024,    1048576, 1024,  1024,   1024,     524288, 512,  262144,
      512,     262144, 512,    32768,  12800,    1600};

  int map[21];
  bool okA = (n_in == 22), okB = (n_in == 21);
  if (okA)
    for (int i = 0; i < 22; ++i)
      if (in_sizes[i] != expA[i]) { okA = false; break; }
  if (okB) {
    int j = 0;
    for (int i = 0; i < 22; ++i) {
      if (i == 1) continue;
      if (in_sizes[j] != expA[i]) { okB = false; break; }
      ++j;
    }
  }
  if (okA) {
    map[0] = 0;
    for (int i = 1; i < 21; ++i) map[i] = i + 1;
  } else if (okB) {
    for (int i = 0; i < 21; ++i) map[i] = i;
  } else {
    map[0] = 0;
    for (int i = 1; i < 21; ++i) map[i] = (i + 1 < n_in) ? i + 1 : n_in - 1;
  }

  const void* z_dyn = d_in[map[0]];
  const void* dtp = d_in[map[1]];
  const void* ut = d_in[map[2]];
  const void* eps = d_in[map[3]];
  const void* W1 = d_in[map[4]];
  const void* b1 = d_in[map[5]];
  const void* g1 = d_in[map[6]];
  const void* be1 = d_in[map[7]];
  const void* W2 = d_in[map[8]];
  const void* b2 = d_in[map[9]];
  const void* g2 = d_in[map[10]];
  const void* be2 = d_in[map[11]];
  const void* W3 = d_in[map[12]];
  const void* b3 = d_in[map[13]];
  const void* Wd1 = d_in[map[14]];
  const void* bd1 = d_in[map[15]];
  const void* Wd2 = d_in[map[16]];
  const void* bd2 = d_in[map[17]];
  const void* Bsde = d_in[map[18]];
  const void* Cm = d_in[map[19]];
  const void* Dm = d_in[map[20]];

  // ws layout (< 38.5 MB, verified >= 40 MB available):
  //  [0,8M)    zf   fp32 4096x512 master state
  //  [8,12M)   zb   bf16 shadow
  //  [12,20M)  Xb   bf16 4096x1024 (X1/A1); after X2: Tb [12,16M), Gb [16,20M)
  //  [20,28M)  Ab   bf16 4096x1024 (X2/A2); post-loop: znf fp32
  //  [28,32M)  Fb   bf16 4096x512
  //  [32M,+5.25M) canon bf16 weights
  //  [37.5M..) s1p(64K) s2p(64K) s1(4K) s2(4K) consts
  char* ws = (char*)d_ws;
  const size_t MB = 1024 * 1024;
  float* zf = (float*)(ws + 0);
  ushort_t* zb = (ushort_t*)(ws + 8 * MB);
  ushort_t* Xb = (ushort_t*)(ws + 12 * MB);
  ushort_t* Tb = (ushort_t*)(ws + 12 * MB);
  ushort_t* Gb = (ushort_t*)(ws + 16 * MB);
  ushort_t* Ab = (ushort_t*)(ws + 20 * MB);
  float* znf = (float*)(ws + 20 * MB);
  ushort_t* Fb = (ushort_t*)(ws + 28 * MB);
  ushort_t* canon = (ushort_t*)(ws + 32 * MB);
  float* s1p = (float*)(ws + 37 * MB + 512 * 1024);
  float* s2p = s1p + 16384;
  float* s1 = s2p + 16384;
  float* s2 = s1 + 1024;
  float* consts = s2 + 1024;

  ushort_t* W1c = canon + 0;
  ushort_t* W2c = canon + 524288;
  ushort_t* W3c = canon + 1572864;
  ushort_t* Wd1c = canon + 2097152;
  ushort_t* Wd2c = canon + 2359296;

  float* out_z = (float*)d_out;
  float* out_y = out_z + 4096 * 512;

  const dim3 blk(256);

  k_detect<<<1, blk, 0, stream>>>(eps, dtp, consts);

  ConvArgs ca;
  ca.src[0] = W1;
  ca.src[1] = W2;
  ca.src[2] = W3;
  ca.src[3] = Wd1;
  ca.src[4] = Wd2;
  k_conv<<<(CONV_TOT / 4 + 255) / 256, blk, 0, stream>>>(ca, consts, canon);

  k_init<<<2048, blk, 0, stream>>>(z_dyn, zf, zb, consts);

  for (int s = 0; s < 8; ++s) {
    // X1 = z @ W1^T + b1 (4096x1024, K=512) -> Xb
    mgemm<0><<<dim3(8, 32), blk, 0, stream>>>(zb, W1c, b1, Xb, consts, 4096, 1024, 512);
    bn_stats<<<dim3(16, 16), blk, 0, stream>>>(Xb, s1p, s2p, 1024);
    k_redstats<<<8, blk, 0, stream>>>(s1p, s2p, s1, s2);
    bn_norm<<<4096, blk, 0, stream>>>(Xb, s1, s2, g1, be1, consts, 1024);  // A1

    // X2 = A1 @ W2^T + b2 (4096x1024, K=1024) -> Ab
    mgemm<0><<<dim3(8, 32), blk, 0, stream>>>(Xb, W2c, b2, Ab, consts, 4096, 1024, 1024);
    bn_stats<<<dim3(16, 16), blk, 0, stream>>>(Ab, s1p, s2p, 1024);
    k_redstats<<<8, blk, 0, stream>>>(s1p, s2p, s1, s2);
    bn_norm<<<4096, blk, 0, stream>>>(Ab, s1, s2, g2, be2, consts, 1024);  // A2

    // F = A2 @ W3^T + b3 (4096x512, K=1024) -> Fb
    mgemm<0><<<dim3(4, 32), blk, 0, stream>>>(Ab, W3c, b3, Fb, consts, 4096, 512, 1024);
    // T = tanh(z @ Wd1^T + bd1) -> Tb (aliases Xb[0:4M), A1 dead)
    mgemm<1><<<dim3(4, 32), blk, 0, stream>>>(zb, Wd1c, bd1, Tb, consts, 4096, 512, 512);
    // G = softplus(T @ Wd2^T + bd2)+1e-5 -> Gb (aliases Xb[4M:8M))
    mgemm<2><<<dim3(4, 32), blk, 0, stream>>>(Tb, Wd2c, bd2, Gb, consts, 4096, 512, 512);

    k_update<<<2048, blk, 0, stream>>>(zf, zb, Fb, Gb, eps,
                                       (unsigned long long)s * 4096 * 512, consts);
  }

  k_final1<<<dim3(8, 64), blk, 0, stream>>>(zf, ut, consts, Bsde, out_z, znf);
  k_final2<<<1024, blk, 0, stream>>>(znf, ut, consts, Cm, Dm, out_y);
}

// Round 9
// 1296.719 us; speedup vs baseline: 2.9402x; 1.1706x over previous
//
#include <hip/hip_runtime.h>

// ---------------------------------------------------------------------------
// ConditionedLatentSDETransition — MI355X (round 9: fusion round)
//
// Verified: inputs fp32 (runtime-detected), outputs fp32, ws >= 40MB,
// dict-order inputs. Round-8 MFMA version passed (1518 us, absmax 0.031).
//
// Round-9 changes:
//  * BN stats fused into X1/X2 GEMM epilogue (LDS+global atomics,
//    16 pre-zeroed stat buffers, single memset) — removes bn_stats/redstats.
//  * Euler update fused into G-GEMM epilogue — removes k_update, Gb buffer.
//  * F/T/G GEMMs use 128x64 tiles -> 256-block grids (full CU coverage).
//  * k_final2: no LDS staging; wave-per-row, coalesced L2-hot C reads.
// ---------------------------------------------------------------------------

typedef unsigned short ushort_t;
typedef __bf16 bf16x8 __attribute__((ext_vector_type(8)));
typedef float f32x4 __attribute__((ext_vector_type(4)));

__device__ __forceinline__ float bf2f(ushort_t s) {
  unsigned u = ((unsigned)s) << 16;
  return __uint_as_float(u);
}
__device__ __forceinline__ ushort_t f2bf(float f) {
  unsigned u = __float_as_uint(f);
  unsigned lsb = (u >> 16) & 1u;
  u += 0x7fffu + lsb;
  return (ushort_t)(u >> 16);
}
__device__ __forceinline__ float ldin(const void* p, size_t i, int f32) {
  return f32 ? ((const float*)p)[i] : bf2f(((const ushort_t*)p)[i]);
}
__device__ __forceinline__ void async16(const void* g, void* l) {
  __builtin_amdgcn_global_load_lds(
      (const __attribute__((address_space(1))) void*)g,
      (__attribute__((address_space(3))) void*)l, 16, 0, 0);
}

// consts: [0]=h, [1]=sqrt_h, [2]=dt, [3]=f32flag
__global__ void k_detect(const void* __restrict__ eps, const void* __restrict__ dtraw,
                         float* __restrict__ consts) {
  __shared__ float mx[256];
  const int t = threadIdx.x;
  const ushort_t* e = (const ushort_t*)eps;
  float m = 0.f;
#pragma unroll
  for (int k = 0; k < 4; ++k) {
    float v = fabsf(bf2f(e[t * 4 + k]));
    if (!(v < 1e30f)) v = 1e30f;
    m = fmaxf(m, v);
  }
  mx[t] = m;
  __syncthreads();
  if (t == 0) {
    float M = 0.f;
    for (int k = 0; k < 256; ++k) M = fmaxf(M, mx[k]);
    const int f32 = (M > 1e3f) ? 1 : 0;
    float dt;
    if (f32) {
      dt = *(const float*)dtraw;
    } else {
      float db = bf2f(*(const ushort_t*)dtraw);
      float df = *(const float*)dtraw;
      dt = (db > 1e-6f && db < 1e3f) ? db : df;
    }
    const float h = dt * 0.125f;
    consts[0] = h;
    consts[1] = sqrtf(fabsf(h) + 1e-8f);
    consts[2] = dt;
    consts[3] = (float)f32;
  }
}

// one-time: convert 5 weight matrices to bf16 in ws
struct ConvArgs { const void* src[5]; };
#define CONV_TOT 2621440

__global__ void k_conv(ConvArgs a, const float* __restrict__ consts,
                       ushort_t* __restrict__ base) {
  constexpr int CUM[6] = {0, 524288, 1572864, 2097152, 2359296, 2621440};
  const int f32 = consts[3] != 0.f;
  const int i = (blockIdx.x * 256 + threadIdx.x) * 4;
  if (i >= CONV_TOT) return;
  int j = 0;
#pragma unroll
  for (int k = 1; k < 5; ++k)
    if (i >= CUM[k]) j = k;
  const int local = i - CUM[j];
  const void* s = a.src[j];
  ushort4 o;
  if (f32) {
    float4 v = ((const float4*)s)[local >> 2];
    o = make_ushort4(f2bf(v.x), f2bf(v.y), f2bf(v.z), f2bf(v.w));
  } else {
    o = ((const ushort4*)s)[local >> 2];
  }
  *(ushort4*)(base + i) = o;
}

// ---------------------------------------------------------------------------
// MFMA GEMM, BM=128, BK=64, BN in {128,64}.
// MODE 0 plain, 1 tanh, 2 softplus+1e-5.
// STATS: accumulate per-column sum/sumsq (pre-activation) into s1/s2.
// FUSE: Euler update fused (needs Fb, zf, zb, eps; skips C store).
// ---------------------------------------------------------------------------
template <int MODE, int BN, int STATS, int FUSE>
__global__ __launch_bounds__(256, 2) void mgemm(
    const ushort_t* __restrict__ A, const ushort_t* __restrict__ W,
    const void* __restrict__ bias, ushort_t* __restrict__ Cout,
    const float* __restrict__ consts, int M, int N, int K,
    float* __restrict__ s1, float* __restrict__ s2,
    const ushort_t* __restrict__ Fb, float* __restrict__ zf,
    ushort_t* __restrict__ zb, const void* __restrict__ eps,
    unsigned long long eoff) {
  __shared__ __bf16 As[128 * 64] __attribute__((aligned(16)));
  __shared__ __bf16 Bs[BN * 64] __attribute__((aligned(16)));

  constexpr int MT = (BN == 128) ? 4 : 2;
  const int f32 = consts[3] != 0.f;
  const int tid = threadIdx.x;
  const int lane = tid & 63;
  const int wave = tid >> 6;
  const int m0 = blockIdx.y * 128, n0 = blockIdx.x * BN;
  const int col = lane & 15;
  const int quad = lane >> 4;
  const int rowBase = (BN == 128) ? (wave >> 1) * 64 : wave * 32;
  const int colBase = (BN == 128) ? (wave & 1) * 64 : 0;

  f32x4 acc[MT][4] = {};

  for (int k0 = 0; k0 < K; k0 += 64) {
#pragma unroll
    for (int j = 0; j < 4; ++j) {  // A: 128x64 = 1024 chunks
      int chunk = j * 256 + tid;
      int row = chunk >> 3;
      int kc = chunk & 7;
      async16(A + (size_t)(m0 + row) * K + k0 + kc * 8, (char*)As + chunk * 16);
    }
#pragma unroll
    for (int j = 0; j < BN / 32; ++j) {  // B: BNx64 chunks
      int chunk = j * 256 + tid;
      int row = chunk >> 3;
      int kc = chunk & 7;
      async16(W + (size_t)(n0 + row) * K + k0 + kc * 8, (char*)Bs + chunk * 16);
    }
    __syncthreads();

#pragma unroll
    for (int kk = 0; kk < 2; ++kk) {
      const int kb = kk * 32 + quad * 8;
      bf16x8 af[MT], bfr[4];
#pragma unroll
      for (int mt = 0; mt < MT; ++mt)
        af[mt] = *(const bf16x8*)&As[(rowBase + mt * 16 + col) * 64 + kb];
#pragma unroll
      for (int nt = 0; nt < 4; ++nt)
        bfr[nt] = *(const bf16x8*)&Bs[(colBase + nt * 16 + col) * 64 + kb];
#pragma unroll
      for (int mt = 0; mt < MT; ++mt)
#pragma unroll
        for (int nt = 0; nt < 4; ++nt)
          acc[mt][nt] = __builtin_amdgcn_mfma_f32_16x16x32_bf16(
              af[mt], bfr[nt], acc[mt][nt], 0, 0, 0);
    }
    __syncthreads();
  }

  // ---- stats scratch in LDS (reuses As; all ds_reads drained) ----
  float* sS = (float*)As;        // [BN]
  float* sQ = (float*)As + BN;   // [BN]
  if (STATS) {
    if (tid < 2 * BN) ((float*)As)[tid] = 0.f;
    __syncthreads();
  }

  const float h = consts[0], sh = consts[1];

#pragma unroll
  for (int nt = 0; nt < 4; ++nt) {
    const int gn = n0 + colBase + nt * 16 + col;
    const float bv = ldin(bias, gn, f32);
    float ls = 0.f, lq = 0.f;
#pragma unroll
    for (int mt = 0; mt < MT; ++mt) {
#pragma unroll
      for (int r = 0; r < 4; ++r) {
        const int gm = m0 + rowBase + mt * 16 + quad * 4 + r;
        float v = acc[mt][nt][r] + bv;
        if (STATS) {
          ls += v;
          lq += v * v;
        }
        if (MODE == 1) {
          v = tanhf(v);
        } else if (MODE == 2) {
          v = fmaxf(v, 0.f) + log1pf(expf(-fabsf(v))) + 1e-5f;
        }
        const size_t o = (size_t)gm * N + gn;
        if (FUSE) {
          // v = g; Euler update: z += h*F + sh*g*eps
          const float e = ldin(eps, eoff + o, f32);
          const float fv = bf2f(Fb[o]);
          const float z = zf[o] + h * fv + sh * v * e;
          zf[o] = z;
          zb[o] = f2bf(z);
        } else {
          Cout[o] = f2bf(v);
        }
      }
    }
    if (STATS) {
      atomicAdd(&sS[colBase + nt * 16 + col], ls);
      atomicAdd(&sQ[colBase + nt * 16 + col], lq);
    }
  }

  if (STATS) {
    __syncthreads();
    if (tid < BN) {
      atomicAdd(&s1[n0 + tid], sS[tid]);
      atomicAdd(&s2[n0 + tid], sQ[tid]);
    }
  }
}

// BN normalize + relu, in-place on bf16 X
__global__ void bn_norm(ushort_t* __restrict__ X, const float* __restrict__ s1,
                        const float* __restrict__ s2, const void* __restrict__ g,
                        const void* __restrict__ be, const float* __restrict__ consts,
                        int N) {
  const int f32 = consts[3] != 0.f;
  const int i = blockIdx.x * 256 + threadIdx.x;
  const int c = (i * 4) % N;
  const float inv = 1.0f / 4096.0f;
  ushort4 x = ((const ushort4*)X)[i];
  float xv[4] = {bf2f(x.x), bf2f(x.y), bf2f(x.z), bf2f(x.w)};
  ushort_t o[4];
#pragma unroll
  for (int j = 0; j < 4; ++j) {
    float mu = s1[c + j] * inv;
    float var = fmaxf(s2[c + j] * inv - mu * mu, 0.f);
    float sc = ldin(g, c + j, f32) * rsqrtf(var + 1e-5f);
    float v = (xv[j] - mu) * sc + ldin(be, c + j, f32);
    o[j] = f2bf(fmaxf(v, 0.f));
  }
  ((ushort4*)X)[i] = make_ushort4(o[0], o[1], o[2], o[3]);
}

// zf (fp32 master) + zb (bf16 shadow) <- z_dyn
__global__ void k_init(const void* __restrict__ z, float* __restrict__ zf,
                       ushort_t* __restrict__ zb, const float* __restrict__ consts) {
  const int f32 = consts[3] != 0.f;
  const int i = blockIdx.x * 256 + threadIdx.x;
  float4 v;
  if (f32) {
    v = ((const float4*)z)[i];
  } else {
    ushort4 u = ((const ushort4*)z)[i];
    v = make_float4(bf2f(u.x), bf2f(u.y), bf2f(u.z), bf2f(u.w));
  }
  ((float4*)zf)[i] = v;
  ((ushort4*)zb)[i] = make_ushort4(f2bf(v.x), f2bf(v.y), f2bf(v.z), f2bf(v.w));
}

// z_next = zf + dt*(ut@Bsde^T): LDS-tiled 64x64, K=64
__global__ __launch_bounds__(256) void k_final1(
    const float* __restrict__ zf, const void* __restrict__ ut,
    const float* __restrict__ consts, const void* __restrict__ Bsde,
    float* __restrict__ out0, float* __restrict__ znf) {
  __shared__ float As[64][68];
  __shared__ float Bs[64][68];
  const float dt = consts[2];
  const int f32 = consts[3] != 0.f;
  const int t = threadIdx.x;
  const int tx = t & 15, ty = t >> 4;
  const int n0 = blockIdx.x * 64, m0 = blockIdx.y * 64;
  const int r = t >> 2;
  const int c0 = (t & 3) * 16;

#pragma unroll
  for (int j = 0; j < 16; ++j) {
    As[c0 + j][r] = ldin(ut, (size_t)(m0 + r) * 64 + c0 + j, f32);
    Bs[c0 + j][r] = ldin(Bsde, (size_t)(n0 + r) * 64 + c0 + j, f32);
  }
  __syncthreads();

  float acc[4][4] = {};
#pragma unroll 8
  for (int kk = 0; kk < 64; ++kk) {
    float a[4], b[4];
    *(float4*)a = *(const float4*)&As[kk][ty * 4];
    *(float4*)b = *(const float4*)&Bs[kk][tx * 4];
#pragma unroll
    for (int i = 0; i < 4; ++i)
#pragma unroll
      for (int j = 0; j < 4; ++j) acc[i][j] += a[i] * b[j];
  }

#pragma unroll
  for (int i = 0; i < 4; ++i) {
    const int m = m0 + ty * 4 + i;
    const size_t o = (size_t)m * 512 + n0 + tx * 4;
    float4 z = *(const float4*)&zf[o];
    float4 v = make_float4(z.x + dt * acc[i][0], z.y + dt * acc[i][1],
                           z.z + dt * acc[i][2], z.w + dt * acc[i][3]);
    *(float4*)&out0[o] = v;
    *(float4*)&znf[o] = v;
  }
}

// yt = znf@C^T + dt*(ut@D^T): wave-per-row, global (L2-hot) C/D reads
__global__ __launch_bounds__(256) void k_final2(
    const float* __restrict__ znf, const void* __restrict__ ut,
    const float* __restrict__ consts, const void* __restrict__ Cm,
    const void* __restrict__ Dm, float* __restrict__ out1) {
  const float dt = consts[2];
  const int f32 = consts[3] != 0.f;
  const int t = threadIdx.x;
  const int lane = t & 63;
  const int m = blockIdx.x * 4 + (t >> 6);
  float z8[8];
#pragma unroll
  for (int i = 0; i < 8; ++i) z8[i] = znf[(size_t)m * 512 + i * 64 + lane];
  const float u = ldin(ut, (size_t)m * 64 + lane, f32);

  for (int j = 0; j < 25; ++j) {
    float p = dt * u * ldin(Dm, (size_t)j * 64 + lane, f32);
#pragma unroll
    for (int i = 0; i < 8; ++i)
      p += z8[i] * ldin(Cm, (size_t)j * 512 + i * 64 + lane, f32);
#pragma unroll
    for (int off = 32; off > 0; off >>= 1) p += __shfl_down(p, off, 64);
    if (lane == 0) out1[m * 25 + j] = p;
  }
}

// ---------------------------------------------------------------------------
extern "C" void kernel_launch(void* const* d_in, const int* in_sizes, int n_in,
                              void* d_out, int out_size, void* d_ws, size_t ws_size,
                              hipStream_t stream) {
  static const int expA[22] = {
      2097152, 524288, 1,      262144, 16777216, 524288, 1024, 1024,
      1024,    1048576, 1024,  1024,   1024,     524288, 512,  262144,
      512,     262144, 512,    32768,  12800,    1600};

  int map[21];
  bool okA = (n_in == 22), okB = (n_in == 21);
  if (okA)
    for (int i = 0; i < 22; ++i)
      if (in_sizes[i] != expA[i]) { okA = false; break; }
  if (okB) {
    int j = 0;
    for (int i = 0; i < 22; ++i) {
      if (i == 1) continue;
      if (in_sizes[j] != expA[i]) { okB = false; break; }
      ++j;
    }
  }
  if (okA) {
    map[0] = 0;
    for (int i = 1; i < 21; ++i) map[i] = i + 1;
  } else if (okB) {
    for (int i = 0; i < 21; ++i) map[i] = i;
  } else {
    map[0] = 0;
    for (int i = 1; i < 21; ++i) map[i] = (i + 1 < n_in) ? i + 1 : n_in - 1;
  }

  const void* z_dyn = d_in[map[0]];
  const void* dtp = d_in[map[1]];
  const void* ut = d_in[map[2]];
  const void* eps = d_in[map[3]];
  const void* W1 = d_in[map[4]];
  const void* b1 = d_in[map[5]];
  const void* g1 = d_in[map[6]];
  const void* be1 = d_in[map[7]];
  const void* W2 = d_in[map[8]];
  const void* b2 = d_in[map[9]];
  const void* g2 = d_in[map[10]];
  const void* be2 = d_in[map[11]];
  const void* W3 = d_in[map[12]];
  const void* b3 = d_in[map[13]];
  const void* Wd1 = d_in[map[14]];
  const void* bd1 = d_in[map[15]];
  const void* Wd2 = d_in[map[16]];
  const void* bd2 = d_in[map[17]];
  const void* Bsde = d_in[map[18]];
  const void* Cm = d_in[map[19]];
  const void* Dm = d_in[map[20]];

  // ws layout (< 38 MB):
  //  [0,8M)    zf fp32;  [8,12M) zb bf16
  //  [12,20M)  Xb bf16 4096x1024 (X1/A1); Tb aliases [12,16M)
  //  [20,28M)  Ab bf16 4096x1024 (X2/A2); znf fp32 aliases post-loop
  //  [28,32M)  Fb bf16 4096x512
  //  [32,37.25M) canon bf16 weights
  //  [37.5M)   stats 16x2048 f32 (128 KB), consts after
  char* ws = (char*)d_ws;
  const size_t MB = 1024 * 1024;
  float* zf = (float*)(ws + 0);
  ushort_t* zb = (ushort_t*)(ws + 8 * MB);
  ushort_t* Xb = (ushort_t*)(ws + 12 * MB);
  ushort_t* Tb = (ushort_t*)(ws + 12 * MB);
  ushort_t* Ab = (ushort_t*)(ws + 20 * MB);
  float* znf = (float*)(ws + 20 * MB);
  ushort_t* Fb = (ushort_t*)(ws + 28 * MB);
  ushort_t* canon = (ushort_t*)(ws + 32 * MB);
  float* stats = (float*)(ws + 37 * MB + 512 * 1024);
  float* consts = stats + 16 * 2048;

  ushort_t* W1c = canon + 0;
  ushort_t* W2c = canon + 524288;
  ushort_t* W3c = canon + 1572864;
  ushort_t* Wd1c = canon + 2097152;
  ushort_t* Wd2c = canon + 2359296;

  float* out_z = (float*)d_out;
  float* out_y = out_z + 4096 * 512;

  const dim3 blk(256);

  k_detect<<<1, blk, 0, stream>>>(eps, dtp, consts);

  ConvArgs ca;
  ca.src[0] = W1;
  ca.src[1] = W2;
  ca.src[2] = W3;
  ca.src[3] = Wd1;
  ca.src[4] = Wd2;
  k_conv<<<(CONV_TOT / 4 + 255) / 256, blk, 0, stream>>>(ca, consts, canon);

  hipMemsetAsync(stats, 0, 16 * 2048 * sizeof(float), stream);
  k_init<<<2048, blk, 0, stream>>>(z_dyn, zf, zb, consts);

  for (int s = 0; s < 8; ++s) {
    float* sA1 = stats + (s * 2 + 0) * 2048;
    float* sA2 = stats + (s * 2 + 1) * 2048;
    const unsigned long long eoff = (unsigned long long)s * 4096 * 512;

    // X1 = z @ W1^T + b1 (4096x1024, K=512), stats fused
    mgemm<0, 128, 1, 0><<<dim3(8, 32), blk, 0, stream>>>(
        zb, W1c, b1, Xb, consts, 4096, 1024, 512, sA1, sA1 + 1024,
        nullptr, nullptr, nullptr, nullptr, 0);
    bn_norm<<<4096, blk, 0, stream>>>(Xb, sA1, sA1 + 1024, g1, be1, consts, 1024);

    // X2 = A1 @ W2^T + b2 (4096x1024, K=1024), stats fused
    mgemm<0, 128, 1, 0><<<dim3(8, 32), blk, 0, stream>>>(
        Xb, W2c, b2, Ab, consts, 4096, 1024, 1024, sA2, sA2 + 1024,
        nullptr, nullptr, nullptr, nullptr, 0);
    bn_norm<<<4096, blk, 0, stream>>>(Ab, sA2, sA2 + 1024, g2, be2, consts, 1024);

    // F = A2 @ W3^T + b3 (4096x512, K=1024), 128x64 tile -> 256 blocks
    mgemm<0, 64, 0, 0><<<dim3(8, 32), blk, 0, stream>>>(
        Ab, W3c, b3, Fb, consts, 4096, 512, 1024, nullptr, nullptr,
        nullptr, nullptr, nullptr, nullptr, 0);
    // T = tanh(z @ Wd1^T + bd1) -> Tb (A1 dead)
    mgemm<1, 64, 0, 0><<<dim3(8, 32), blk, 0, stream>>>(
        zb, Wd1c, bd1, Tb, consts, 4096, 512, 512, nullptr, nullptr,
        nullptr, nullptr, nullptr, nullptr, 0);
    // G + Euler update fused: z += h*F + sqrt_h*G*eps[s]
    mgemm<2, 64, 0, 1><<<dim3(8, 32), blk, 0, stream>>>(
        Tb, Wd2c, bd2, nullptr, consts, 4096, 512, 512, nullptr, nullptr,
        Fb, zf, zb, eps, eoff);
  }

  k_final1<<<dim3(8, 64), blk, 0, stream>>>(zf, ut, consts, Bsde, out_z, znf);
  k_final2<<<1024, blk, 0, stream>>>(znf, ut, consts, Cm, Dm, out_y);
}

// Round 10
// 1110.847 us; speedup vs baseline: 3.4322x; 1.1673x over previous
//
#include <hip/hip_runtime.h>

// ---------------------------------------------------------------------------
// ConditionedLatentSDETransition — MI355X (round 10: occupancy round)
//
// Verified: inputs fp32 (runtime-detected), outputs fp32, ws >= 40MB,
// dict-order inputs. Round-9: 1297 us, absmax 0.0156.
//
// Round-10 changes:
//  * All GEMM grids -> 512 blocks (2-4 blocks/CU, 8-16 waves/CU) so the
//    global_load_lds barrier drain is hidden by co-resident blocks:
//      X1/X2: BM=128,BN=64, __launch_bounds__(256,3)
//      F/T/G: BM=64, BN=64, __launch_bounds__(256,4)
//  * X1/X2 skip bias entirely (BatchNorm is shift-invariant -> exact).
// ---------------------------------------------------------------------------

typedef unsigned short ushort_t;
typedef __bf16 bf16x8 __attribute__((ext_vector_type(8)));
typedef float f32x4 __attribute__((ext_vector_type(4)));

__device__ __forceinline__ float bf2f(ushort_t s) {
  unsigned u = ((unsigned)s) << 16;
  return __uint_as_float(u);
}
__device__ __forceinline__ ushort_t f2bf(float f) {
  unsigned u = __float_as_uint(f);
  unsigned lsb = (u >> 16) & 1u;
  u += 0x7fffu + lsb;
  return (ushort_t)(u >> 16);
}
__device__ __forceinline__ float ldin(const void* p, size_t i, int f32) {
  return f32 ? ((const float*)p)[i] : bf2f(((const ushort_t*)p)[i]);
}
__device__ __forceinline__ void async16(const void* g, void* l) {
  __builtin_amdgcn_global_load_lds(
      (const __attribute__((address_space(1))) void*)g,
      (__attribute__((address_space(3))) void*)l, 16, 0, 0);
}

// consts: [0]=h, [1]=sqrt_h, [2]=dt, [3]=f32flag
__global__ void k_detect(const void* __restrict__ eps, const void* __restrict__ dtraw,
                         float* __restrict__ consts) {
  __shared__ float mx[256];
  const int t = threadIdx.x;
  const ushort_t* e = (const ushort_t*)eps;
  float m = 0.f;
#pragma unroll
  for (int k = 0; k < 4; ++k) {
    float v = fabsf(bf2f(e[t * 4 + k]));
    if (!(v < 1e30f)) v = 1e30f;
    m = fmaxf(m, v);
  }
  mx[t] = m;
  __syncthreads();
  if (t == 0) {
    float M = 0.f;
    for (int k = 0; k < 256; ++k) M = fmaxf(M, mx[k]);
    const int f32 = (M > 1e3f) ? 1 : 0;
    float dt;
    if (f32) {
      dt = *(const float*)dtraw;
    } else {
      float db = bf2f(*(const ushort_t*)dtraw);
      float df = *(const float*)dtraw;
      dt = (db > 1e-6f && db < 1e3f) ? db : df;
    }
    const float h = dt * 0.125f;
    consts[0] = h;
    consts[1] = sqrtf(fabsf(h) + 1e-8f);
    consts[2] = dt;
    consts[3] = (float)f32;
  }
}

// one-time: convert 5 weight matrices to bf16 in ws
struct ConvArgs { const void* src[5]; };
#define CONV_TOT 2621440

__global__ void k_conv(ConvArgs a, const float* __restrict__ consts,
                       ushort_t* __restrict__ base) {
  constexpr int CUM[6] = {0, 524288, 1572864, 2097152, 2359296, 2621440};
  const int f32 = consts[3] != 0.f;
  const int i = (blockIdx.x * 256 + threadIdx.x) * 4;
  if (i >= CONV_TOT) return;
  int j = 0;
#pragma unroll
  for (int k = 1; k < 5; ++k)
    if (i >= CUM[k]) j = k;
  const int local = i - CUM[j];
  const void* s = a.src[j];
  ushort4 o;
  if (f32) {
    float4 v = ((const float4*)s)[local >> 2];
    o = make_ushort4(f2bf(v.x), f2bf(v.y), f2bf(v.z), f2bf(v.w));
  } else {
    o = ((const ushort4*)s)[local >> 2];
  }
  *(ushort4*)(base + i) = o;
}

// ---------------------------------------------------------------------------
// MFMA GEMM. BM in {64,128}, BN=64, BK=64, 256 threads (4 waves).
// BM=128: wave -> 32 rows x 64 cols (MT=2). BM=64: 16 rows x 64 cols (MT=1).
// MODE 0 plain, 1 tanh, 2 softplus+1e-5. BIAS=0 skips bias (BN-invariant).
// STATS: per-column sum/sumsq (pre-activation) -> s1/s2 via atomics.
// FUSE: Euler update fused (reads Fb,zf,eps; writes zf,zb; no C store).
// ---------------------------------------------------------------------------
template <int MODE, int BM, int STATS, int FUSE, int BIAS, int MINW>
__global__ __launch_bounds__(256, MINW) void mgemm(
    const ushort_t* __restrict__ A, const ushort_t* __restrict__ W,
    const void* __restrict__ bias, ushort_t* __restrict__ Cout,
    const float* __restrict__ consts, int M, int N, int K,
    float* __restrict__ s1, float* __restrict__ s2,
    const ushort_t* __restrict__ Fb, float* __restrict__ zf,
    ushort_t* __restrict__ zb, const void* __restrict__ eps,
    unsigned long long eoff) {
  __shared__ __bf16 As[BM * 64] __attribute__((aligned(16)));
  __shared__ __bf16 Bs[64 * 64] __attribute__((aligned(16)));

  constexpr int MT = BM / 64;  // 2 for BM=128, 1 for BM=64
  const int f32 = consts[3] != 0.f;
  const int tid = threadIdx.x;
  const int lane = tid & 63;
  const int wave = tid >> 6;
  const int m0 = blockIdx.y * BM, n0 = blockIdx.x * 64;
  const int col = lane & 15;
  const int quad = lane >> 4;
  const int rowBase = wave * (BM / 4);

  f32x4 acc[MT][4] = {};

  for (int k0 = 0; k0 < K; k0 += 64) {
#pragma unroll
    for (int j = 0; j < BM / 32; ++j) {  // A: BM x 64 -> BM*8 chunks
      int chunk = j * 256 + tid;
      int row = chunk >> 3;
      int kc = chunk & 7;
      async16(A + (size_t)(m0 + row) * K + k0 + kc * 8, (char*)As + chunk * 16);
    }
#pragma unroll
    for (int j = 0; j < 2; ++j) {  // B: 64 x 64 -> 512 chunks
      int chunk = j * 256 + tid;
      int row = chunk >> 3;
      int kc = chunk & 7;
      async16(W + (size_t)(n0 + row) * K + k0 + kc * 8, (char*)Bs + chunk * 16);
    }
    __syncthreads();

#pragma unroll
    for (int kk = 0; kk < 2; ++kk) {
      const int kb = kk * 32 + quad * 8;
      bf16x8 af[MT], bfr[4];
#pragma unroll
      for (int mt = 0; mt < MT; ++mt)
        af[mt] = *(const bf16x8*)&As[(rowBase + mt * 16 + col) * 64 + kb];
#pragma unroll
      for (int nt = 0; nt < 4; ++nt)
        bfr[nt] = *(const bf16x8*)&Bs[(nt * 16 + col) * 64 + kb];
#pragma unroll
      for (int mt = 0; mt < MT; ++mt)
#pragma unroll
        for (int nt = 0; nt < 4; ++nt)
          acc[mt][nt] = __builtin_amdgcn_mfma_f32_16x16x32_bf16(
              af[mt], bfr[nt], acc[mt][nt], 0, 0, 0);
    }
    __syncthreads();
  }

  // stats scratch in LDS (reuses As; safe: all ds_reads drained by barrier)
  float* sS = (float*)As;       // [64]
  float* sQ = (float*)As + 64;  // [64]
  if (STATS) {
    if (tid < 128) ((float*)As)[tid] = 0.f;
    __syncthreads();
  }

  const float h = consts[0], sh = consts[1];

#pragma unroll
  for (int nt = 0; nt < 4; ++nt) {
    const int gn = n0 + nt * 16 + col;
    const float bv = BIAS ? ldin(bias, gn, f32) : 0.f;
    float ls = 0.f, lq = 0.f;
#pragma unroll
    for (int mt = 0; mt < MT; ++mt) {
#pragma unroll
      for (int r = 0; r < 4; ++r) {
        const int gm = m0 + rowBase + mt * 16 + quad * 4 + r;
        float v = acc[mt][nt][r] + bv;
        if (STATS) {
          ls += v;
          lq += v * v;
        }
        if (MODE == 1) {
          v = tanhf(v);
        } else if (MODE == 2) {
          v = fmaxf(v, 0.f) + log1pf(expf(-fabsf(v))) + 1e-5f;
        }
        const size_t o = (size_t)gm * N + gn;
        if (FUSE) {
          const float e = ldin(eps, eoff + o, f32);
          const float fv = bf2f(Fb[o]);
          const float z = zf[o] + h * fv + sh * v * e;
          zf[o] = z;
          zb[o] = f2bf(z);
        } else {
          Cout[o] = f2bf(v);
        }
      }
    }
    if (STATS) {
      atomicAdd(&sS[nt * 16 + col], ls);
      atomicAdd(&sQ[nt * 16 + col], lq);
    }
  }

  if (STATS) {
    __syncthreads();
    if (tid < 64) {
      atomicAdd(&s1[n0 + tid], sS[tid]);
      atomicAdd(&s2[n0 + tid], sQ[tid]);
    }
  }
}

// BN normalize + relu, in-place on bf16 X
__global__ void bn_norm(ushort_t* __restrict__ X, const float* __restrict__ s1,
                        const float* __restrict__ s2, const void* __restrict__ g,
                        const void* __restrict__ be, const float* __restrict__ consts,
                        int N) {
  const int f32 = consts[3] != 0.f;
  const int i = blockIdx.x * 256 + threadIdx.x;
  const int c = (i * 4) % N;
  const float inv = 1.0f / 4096.0f;
  ushort4 x = ((const ushort4*)X)[i];
  float xv[4] = {bf2f(x.x), bf2f(x.y), bf2f(x.z), bf2f(x.w)};
  ushort_t o[4];
#pragma unroll
  for (int j = 0; j < 4; ++j) {
    float mu = s1[c + j] * inv;
    float var = fmaxf(s2[c + j] * inv - mu * mu, 0.f);
    float sc = ldin(g, c + j, f32) * rsqrtf(var + 1e-5f);
    float v = (xv[j] - mu) * sc + ldin(be, c + j, f32);
    o[j] = f2bf(fmaxf(v, 0.f));
  }
  ((ushort4*)X)[i] = make_ushort4(o[0], o[1], o[2], o[3]);
}

// zf (fp32 master) + zb (bf16 shadow) <- z_dyn
__global__ void k_init(const void* __restrict__ z, float* __restrict__ zf,
                       ushort_t* __restrict__ zb, const float* __restrict__ consts) {
  const int f32 = consts[3] != 0.f;
  const int i = blockIdx.x * 256 + threadIdx.x;
  float4 v;
  if (f32) {
    v = ((const float4*)z)[i];
  } else {
    ushort4 u = ((const ushort4*)z)[i];
    v = make_float4(bf2f(u.x), bf2f(u.y), bf2f(u.z), bf2f(u.w));
  }
  ((float4*)zf)[i] = v;
  ((ushort4*)zb)[i] = make_ushort4(f2bf(v.x), f2bf(v.y), f2bf(v.z), f2bf(v.w));
}

// z_next = zf + dt*(ut@Bsde^T): LDS-tiled 64x64, K=64
__global__ __launch_bounds__(256) void k_final1(
    const float* __restrict__ zf, const void* __restrict__ ut,
    const float* __restrict__ consts, const void* __restrict__ Bsde,
    float* __restrict__ out0, float* __restrict__ znf) {
  __shared__ float As[64][68];
  __shared__ float Bs[64][68];
  const float dt = consts[2];
  const int f32 = consts[3] != 0.f;
  const int t = threadIdx.x;
  const int tx = t & 15, ty = t >> 4;
  const int n0 = blockIdx.x * 64, m0 = blockIdx.y * 64;
  const int r = t >> 2;
  const int c0 = (t & 3) * 16;

#pragma unroll
  for (int j = 0; j < 16; ++j) {
    As[c0 + j][r] = ldin(ut, (size_t)(m0 + r) * 64 + c0 + j, f32);
    Bs[c0 + j][r] = ldin(Bsde, (size_t)(n0 + r) * 64 + c0 + j, f32);
  }
  __syncthreads();

  float acc[4][4] = {};
#pragma unroll 8
  for (int kk = 0; kk < 64; ++kk) {
    float a[4], b[4];
    *(float4*)a = *(const float4*)&As[kk][ty * 4];
    *(float4*)b = *(const float4*)&Bs[kk][tx * 4];
#pragma unroll
    for (int i = 0; i < 4; ++i)
#pragma unroll
      for (int j = 0; j < 4; ++j) acc[i][j] += a[i] * b[j];
  }

#pragma unroll
  for (int i = 0; i < 4; ++i) {
    const int m = m0 + ty * 4 + i;
    const size_t o = (size_t)m * 512 + n0 + tx * 4;
    float4 z = *(const float4*)&zf[o];
    float4 v = make_float4(z.x + dt * acc[i][0], z.y + dt * acc[i][1],
                           z.z + dt * acc[i][2], z.w + dt * acc[i][3]);
    *(float4*)&out0[o] = v;
    *(float4*)&znf[o] = v;
  }
}

// yt = znf@C^T + dt*(ut@D^T): wave-per-row, L2-hot coalesced C/D reads
__global__ __launch_bounds__(256) void k_final2(
    const float* __restrict__ znf, const void* __restrict__ ut,
    const float* __restrict__ consts, const void* __restrict__ Cm,
    const void* __restrict__ Dm, float* __restrict__ out1) {
  const float dt = consts[2];
  const int f32 = consts[3] != 0.f;
  const int t = threadIdx.x;
  const int lane = t & 63;
  const int m = blockIdx.x * 4 + (t >> 6);
  float z8[8];
#pragma unroll
  for (int i = 0; i < 8; ++i) z8[i] = znf[(size_t)m * 512 + i * 64 + lane];
  const float u = ldin(ut, (size_t)m * 64 + lane, f32);

  for (int j = 0; j < 25; ++j) {
    float p = dt * u * ldin(Dm, (size_t)j * 64 + lane, f32);
#pragma unroll
    for (int i = 0; i < 8; ++i)
      p += z8[i] * ldin(Cm, (size_t)j * 512 + i * 64 + lane, f32);
#pragma unroll
    for (int off = 32; off > 0; off >>= 1) p += __shfl_down(p, off, 64);
    if (lane == 0) out1[m * 25 + j] = p;
  }
}

// ---------------------------------------------------------------------------
extern "C" void kernel_launch(void* const* d_in, const int* in_sizes, int n_in,
                              void* d_out, int out_size, void* d_ws, size_t ws_size,
                              hipStream_t stream) {
  static const int expA[22] = {
      2097152, 524288, 1,      262144, 16777216, 524288, 1024, 1024,
      1024,    1048576, 1024,  1024,   1024,     524288, 512,  262144,
      512,     262144, 512,    32768,  12800,    1600};

  int map[21];
  bool okA = (n_in == 22), okB = (n_in == 21);
  if (okA)
    for (int i = 0; i < 22; ++i)
      if (in_sizes[i] != expA[i]) { okA = false; break; }
  if (okB) {
    int j = 0;
    for (int i = 0; i < 22; ++i) {
      if (i == 1) continue;
      if (in_sizes[j] != expA[i]) { okB = false; break; }
      ++j;
    }
  }
  if (okA) {
    map[0] = 0;
    for (int i = 1; i < 21; ++i) map[i] = i + 1;
  } else if (okB) {
    for (int i = 0; i < 21; ++i) map[i] = i;
  } else {
    map[0] = 0;
    for (int i = 1; i < 21; ++i) map[i] = (i + 1 < n_in) ? i + 1 : n_in - 1;
  }

  const void* z_dyn = d_in[map[0]];
  const void* dtp = d_in[map[1]];
  const void* ut = d_in[map[2]];
  const void* eps = d_in[map[3]];
  const void* W1 = d_in[map[4]];
  const void* g1 = d_in[map[6]];
  const void* be1 = d_in[map[7]];
  const void* W2 = d_in[map[8]];
  const void* g2 = d_in[map[10]];
  const void* be2 = d_in[map[11]];
  const void* W3 = d_in[map[12]];
  const void* b3 = d_in[map[13]];
  const void* Wd1 = d_in[map[14]];
  const void* bd1 = d_in[map[15]];
  const void* Wd2 = d_in[map[16]];
  const void* bd2 = d_in[map[17]];
  const void* Bsde = d_in[map[18]];
  const void* Cm = d_in[map[19]];
  const void* Dm = d_in[map[20]];

  // ws layout (< 38 MB):
  //  [0,8M) zf fp32; [8,12M) zb bf16
  //  [12,20M) Xb bf16 (X1/A1); Tb aliases [12,16M)
  //  [20,28M) Ab bf16 (X2/A2); znf fp32 aliases post-loop
  //  [28,32M) Fb bf16; [32,37.25M) canon weights; [37.5M) stats+consts
  char* ws = (char*)d_ws;
  const size_t MB = 1024 * 1024;
  float* zf = (float*)(ws + 0);
  ushort_t* zb = (ushort_t*)(ws + 8 * MB);
  ushort_t* Xb = (ushort_t*)(ws + 12 * MB);
  ushort_t* Tb = (ushort_t*)(ws + 12 * MB);
  ushort_t* Ab = (ushort_t*)(ws + 20 * MB);
  float* znf = (float*)(ws + 20 * MB);
  ushort_t* Fb = (ushort_t*)(ws + 28 * MB);
  ushort_t* canon = (ushort_t*)(ws + 32 * MB);
  float* stats = (float*)(ws + 37 * MB + 512 * 1024);
  float* consts = stats + 16 * 2048;

  ushort_t* W1c = canon + 0;
  ushort_t* W2c = canon + 524288;
  ushort_t* W3c = canon + 1572864;
  ushort_t* Wd1c = canon + 2097152;
  ushort_t* Wd2c = canon + 2359296;

  float* out_z = (float*)d_out;
  float* out_y = out_z + 4096 * 512;

  const dim3 blk(256);

  k_detect<<<1, blk, 0, stream>>>(eps, dtp, consts);

  ConvArgs ca;
  ca.src[0] = W1;
  ca.src[1] = W2;
  ca.src[2] = W3;
  ca.src[3] = Wd1;
  ca.src[4] = Wd2;
  k_conv<<<(CONV_TOT / 4 + 255) / 256, blk, 0, stream>>>(ca, consts, canon);

  hipMemsetAsync(stats, 0, 16 * 2048 * sizeof(float), stream);
  k_init<<<2048, blk, 0, stream>>>(z_dyn, zf, zb, consts);

  for (int s = 0; s < 8; ++s) {
    float* sA1 = stats + (s * 2 + 0) * 2048;
    float* sA2 = stats + (s * 2 + 1) * 2048;
    const unsigned long long eoff = (unsigned long long)s * 4096 * 512;

    // X1 = z @ W1^T (4096x1024, K=512) — bias dropped (BN-invariant), stats fused
    mgemm<0, 128, 1, 0, 0, 3><<<dim3(16, 32), blk, 0, stream>>>(
        zb, W1c, nullptr, Xb, consts, 4096, 1024, 512, sA1, sA1 + 1024,
        nullptr, nullptr, nullptr, nullptr, 0);
    bn_norm<<<4096, blk, 0, stream>>>(Xb, sA1, sA1 + 1024, g1, be1, consts, 1024);

    // X2 = A1 @ W2^T (4096x1024, K=1024) — bias dropped, stats fused
    mgemm<0, 128, 1, 0, 0, 3><<<dim3(16, 32), blk, 0, stream>>>(
        Xb, W2c, nullptr, Ab, consts, 4096, 1024, 1024, sA2, sA2 + 1024,
        nullptr, nullptr, nullptr, nullptr, 0);
    bn_norm<<<4096, blk, 0, stream>>>(Ab, sA2, sA2 + 1024, g2, be2, consts, 1024);

    // F = A2 @ W3^T + b3 (4096x512, K=1024), BM=64 -> 512 blocks
    mgemm<0, 64, 0, 0, 1, 4><<<dim3(8, 64), blk, 0, stream>>>(
        Ab, W3c, b3, Fb, consts, 4096, 512, 1024, nullptr, nullptr,
        nullptr, nullptr, nullptr, nullptr, 0);
    // T = tanh(z @ Wd1^T + bd1), BM=64
    mgemm<1, 64, 0, 0, 1, 4><<<dim3(8, 64), blk, 0, stream>>>(
        zb, Wd1c, bd1, Tb, consts, 4096, 512, 512, nullptr, nullptr,
        nullptr, nullptr, nullptr, nullptr, 0);
    // G + Euler update fused: z += h*F + sqrt_h*G*eps[s], BM=64
    mgemm<2, 64, 0, 1, 1, 4><<<dim3(8, 64), blk, 0, stream>>>(
        Tb, Wd2c, bd2, nullptr, consts, 4096, 512, 512, nullptr, nullptr,
        Fb, zf, zb, eps, eoff);
  }

  k_final1<<<dim3(8, 64), blk, 0, stream>>>(zf, ut, consts, Bsde, out_z, znf);
  k_final2<<<1024, blk, 0, stream>>>(znf, ut, consts, Cm, Dm, out_y);
}